// Round 4
// baseline (27.813 us; speedup 1.0000x reference)
//
#include <hip/hip_runtime.h>

// SparseNodeLinear, sparsity-aware single-pass:
//   out[b,f,n] = sum_{k: em[n,k]==0} x[b,k,n] * w[n,k,f] + bias[f,n]
// x: [B,K,N] f32, w: [N,K,F] f32, bias: [F,N] f32, em: [N,K] int32, out: [B,F,N] f32
// B=8, N=2048, K=2049, F=32.  em is ~98.4% nonzero => ~34 active k per node.
//
// One block per node. Single pass: 9 register-resident em chunks -> 9 ballots ->
// 36-count LDS prefix -> ordered active list (2 barriers), then one gather phase,
// one compute phase (ct~34 so all 8 kphases busy), one LDS reduction.

constexpr int N_ = 2048;
constexpr int K_ = 2049;
constexpr int F_ = 32;
constexpr int B_ = 8;
constexpr int CH = 9;     // ceil(K_/256)
constexpr int CAPK = 192; // max active k per node (data mean ~34, huge margin)

__global__ __launch_bounds__(256, 8) void snl_sparse1(
    const float* __restrict__ x,
    const float* __restrict__ w,
    const float* __restrict__ bias,
    const int*   __restrict__ em,
    float* __restrict__ out)
{
    const int n      = blockIdx.x;
    const int t      = threadIdx.x;
    const int lane   = t & 63;
    const int wid    = t >> 6;   // 0..3
    const int kphase = t >> 5;   // 0..7
    const int f      = t & 31;   // 0..31

    __shared__ int   s_cnt[CH * 4];
    __shared__ int   s_idx[CAPK];
    __shared__ float s_x[CAPK][B_];
    __shared__ float s_red[8][B_][F_];

    const int*   emn = em + (size_t)n * K_;
    const float* wn  = w  + (size_t)n * K_ * F_;

    // --- scan: all 9 em chunks issued up-front (one exposed latency) ---
    int emr[CH];
    #pragma unroll
    for (int c = 0; c < CH; ++c) {
        const int k = c * 256 + t;
        emr[c] = (k < K_) ? emn[k] : 1;
    }
    unsigned long long bal[CH];
    #pragma unroll
    for (int c = 0; c < CH; ++c) {
        bal[c] = __ballot(emr[c] == 0);
        if (lane == 0) s_cnt[c * 4 + wid] = __popcll(bal[c]);
    }
    __syncthreads();

    // --- per-(chunk, wave) bases + total, computed redundantly per thread ---
    int pre[CH];
    int ct = 0;
    #pragma unroll
    for (int c = 0; c < CH; ++c) {
        const int c0 = s_cnt[c * 4 + 0];
        const int c1 = s_cnt[c * 4 + 1];
        const int c2 = s_cnt[c * 4 + 2];
        const int c3 = s_cnt[c * 4 + 3];
        pre[c] = ct + ((wid > 0) ? c0 : 0) + ((wid > 1) ? c1 : 0) + ((wid > 2) ? c2 : 0);
        ct += c0 + c1 + c2 + c3;
    }
    const int ctc = (ct < CAPK) ? ct : CAPK;

    // --- write ordered active list ---
    const unsigned long long lowmask = (lane == 63) ? ~0ull >> 1 : ((1ull << lane) - 1ull);
    #pragma unroll
    for (int c = 0; c < CH; ++c) {
        if (emr[c] == 0) {
            const int pos = pre[c] + __popcll(bal[c] & lowmask);
            if (pos < CAPK) s_idx[pos] = c * 256 + t;
        }
    }
    __syncthreads();

    // --- gather x[b, k_j, n] into LDS (all loads in flight together) ---
    for (int jj = t; jj < ctc * B_; jj += 256) {
        const int j = jj >> 3;
        const int b = jj & 7;
        s_x[j][b] = x[((size_t)b * K_ + s_idx[j]) * N_ + n];
    }
    __syncthreads();

    // --- compute: thread (kphase, f) sums j = kphase, kphase+8, ... ---
    float acc[B_];
    #pragma unroll
    for (int b = 0; b < B_; ++b) acc[b] = 0.f;

    for (int j = kphase; j < ctc; j += 8) {
        const int kj   = s_idx[j];
        const float wv = wn[(size_t)kj * F_ + f];   // coalesced 128B per kphase group
        const float4 x0 = *reinterpret_cast<const float4*>(&s_x[j][0]);
        const float4 x1 = *reinterpret_cast<const float4*>(&s_x[j][4]);
        acc[0] = fmaf(x0.x, wv, acc[0]);
        acc[1] = fmaf(x0.y, wv, acc[1]);
        acc[2] = fmaf(x0.z, wv, acc[2]);
        acc[3] = fmaf(x0.w, wv, acc[3]);
        acc[4] = fmaf(x1.x, wv, acc[4]);
        acc[5] = fmaf(x1.y, wv, acc[5]);
        acc[6] = fmaf(x1.z, wv, acc[6]);
        acc[7] = fmaf(x1.w, wv, acc[7]);
    }

    // --- cross-kphase reduction ---
    #pragma unroll
    for (int b = 0; b < B_; ++b) s_red[kphase][b][f] = acc[b];
    __syncthreads();

    {
        const int b  = t >> 5;
        const int ff = t & 31;
        float s = 0.f;
        #pragma unroll
        for (int p = 0; p < 8; ++p) s += s_red[p][b][ff];
        out[((size_t)b * F_ + ff) * N_ + n] = s + bias[(size_t)ff * N_ + n];
    }
}

extern "C" void kernel_launch(void* const* d_in, const int* in_sizes, int n_in,
                              void* d_out, int out_size, void* d_ws, size_t ws_size,
                              hipStream_t stream) {
    const float* x    = (const float*)d_in[0];
    const float* w    = (const float*)d_in[1];
    const float* bias = (const float*)d_in[2];
    const int*   em   = (const int*)d_in[3];
    float*       out  = (float*)d_out;

    snl_sparse1<<<dim3(N_), dim3(256), 0, stream>>>(x, w, bias, em, out);
}

// Round 5
// 21.039 us; speedup vs baseline: 1.3220x; 1.3220x over previous
//
#include <hip/hip_runtime.h>

// SparseNodeLinear, latency-optimized sparse single-pass:
//   out[b,f,n] = sum_{k: em[n,k]==0} x[b,k,n] * w[n,k,f] + bias[f,n]
// x: [B,K,N] f32, w: [N,K,F] f32, bias: [F,N] f32, em: [N,K] int32, out: [B,F,N] f32
// B=8, N=2048, K=2049, F=32.  ~34 active k per node (mask ~98.4% True).
//
// One block per node. Dependency-chain minimized:
//   em loads (9 indep) -> ballot/prefix; discovering thread issues its 8 x loads
//   and writes s_x itself (x latency hidden under scan) -> single barrier ->
//   compute with ALL w loads preloaded into registers (uniform padded trip count).
// XCD-aware n mapping keeps adjacent n on one XCD (write-combining + bias/x locality).

constexpr int N_ = 2048;
constexpr int K_ = 2049;
constexpr int F_ = 32;
constexpr int B_ = 8;
constexpr int CH = 9;      // ceil(K/256)
constexpr int CAPK = 192;  // max active k per node (mean ~34, sigma ~5.6; guarded)

__global__ __launch_bounds__(256, 8) void snl_sparse2(
    const float* __restrict__ x,
    const float* __restrict__ w,
    const float* __restrict__ bias,
    const int*   __restrict__ em,
    float* __restrict__ out)
{
    const int bid = blockIdx.x;
    const int n   = ((bid & 7) << 8) | (bid >> 3);   // XCD-contiguous n chunks
    const int t   = threadIdx.x;
    const int lane   = t & 63;
    const int wid    = t >> 6;   // 0..3
    const int kphase = t >> 5;   // 0..7
    const int f      = t & 31;   // 0..31

    __shared__ int   s_cnt[CH * 4];
    __shared__ int   s_idx[CAPK];
    __shared__ float s_x[CAPK][B_];
    __shared__ float s_red[8][B_][F_];

    const int*   emn = em + (size_t)n * K_;
    const float* wn  = w  + (size_t)n * K_ * F_;

    // --- phase 1: 9 independent em loads, issued immediately ---
    int emr[CH];
    #pragma unroll
    for (int c = 0; c < CH - 1; ++c) emr[c] = emn[c * 256 + t];
    emr[CH - 1] = (t == 0) ? emn[2048] : 1;   // K=2049 tail

    // --- phase 2: ballots, per-(chunk,wave) counts, per-thread offsets ---
    const unsigned long long lowmask = (1ull << lane) - 1ull;
    int woff[CH];
    unsigned actmask = 0;
    #pragma unroll
    for (int c = 0; c < CH; ++c) {
        const unsigned long long bal = __ballot(emr[c] == 0);
        if (lane == 0) s_cnt[c * 4 + wid] = __popcll(bal);
        woff[c] = __popcll(bal & lowmask);
        actmask |= (emr[c] == 0 ? 1u : 0u) << c;
    }
    __syncthreads();

    // --- phase 3: bases; discovering thread writes s_idx AND gathers its x row ---
    int ct = 0;
    #pragma unroll
    for (int c = 0; c < CH; ++c) {
        const int c0 = s_cnt[c * 4 + 0];
        const int c1 = s_cnt[c * 4 + 1];
        const int c2 = s_cnt[c * 4 + 2];
        const int c3 = s_cnt[c * 4 + 3];
        const int base = ct + ((wid > 0) ? c0 : 0) + ((wid > 1) ? c1 : 0) + ((wid > 2) ? c2 : 0);
        ct += c0 + c1 + c2 + c3;
        if ((actmask >> c) & 1u) {
            const int pos = base + woff[c];
            const int k   = c * 256 + t;
            if (pos < CAPK) {
                s_idx[pos] = k;
                const float* xp = x + (size_t)k * N_ + n;
                const float xv0 = xp[0 * (size_t)K_ * N_];
                const float xv1 = xp[1 * (size_t)K_ * N_];
                const float xv2 = xp[2 * (size_t)K_ * N_];
                const float xv3 = xp[3 * (size_t)K_ * N_];
                const float xv4 = xp[4 * (size_t)K_ * N_];
                const float xv5 = xp[5 * (size_t)K_ * N_];
                const float xv6 = xp[6 * (size_t)K_ * N_];
                const float xv7 = xp[7 * (size_t)K_ * N_];
                *reinterpret_cast<float4*>(&s_x[pos][0]) = make_float4(xv0, xv1, xv2, xv3);
                *reinterpret_cast<float4*>(&s_x[pos][4]) = make_float4(xv4, xv5, xv6, xv7);
            }
        }
    }

    // --- pad list to multiple of 8 (uniform compute trip count) ---
    const int ctc = (ct < CAPK) ? ct : CAPK;
    const int ctp = (ctc + 7) & ~7;
    if (t < ctp - ctc) {
        s_idx[ctc + t] = 0;   // k=0: valid address, multiplied by zero below
        *reinterpret_cast<float4*>(&s_x[ctc + t][0]) = make_float4(0.f, 0.f, 0.f, 0.f);
        *reinterpret_cast<float4*>(&s_x[ctc + t][4]) = make_float4(0.f, 0.f, 0.f, 0.f);
    }
    __syncthreads();

    // --- phase 4: compute. Preload ALL w values (tc <= 8 fast path) ---
    const int tc = ctp >> 3;   // j's per kphase, uniform across block
    float acc[B_];
    #pragma unroll
    for (int b = 0; b < B_; ++b) acc[b] = 0.f;

    float wr[8];
    #pragma unroll
    for (int i = 0; i < 8; ++i) {
        if (i < tc) {
            const int j = kphase + i * 8;
            wr[i] = wn[(size_t)s_idx[j] * F_ + f];   // all misses in flight together
        }
    }
    #pragma unroll
    for (int i = 0; i < 8; ++i) {
        if (i < tc) {
            const int j = kphase + i * 8;
            const float4 x0 = *reinterpret_cast<const float4*>(&s_x[j][0]);
            const float4 x1 = *reinterpret_cast<const float4*>(&s_x[j][4]);
            const float wv = wr[i];
            acc[0] = fmaf(x0.x, wv, acc[0]);
            acc[1] = fmaf(x0.y, wv, acc[1]);
            acc[2] = fmaf(x0.z, wv, acc[2]);
            acc[3] = fmaf(x0.w, wv, acc[3]);
            acc[4] = fmaf(x1.x, wv, acc[4]);
            acc[5] = fmaf(x1.y, wv, acc[5]);
            acc[6] = fmaf(x1.z, wv, acc[6]);
            acc[7] = fmaf(x1.w, wv, acc[7]);
        }
    }
    // fallback (statistically never taken; correctness guard for ctp > 64)
    for (int j = kphase + 64; j < ctp; j += 8) {
        const float wv = wn[(size_t)s_idx[j] * F_ + f];
        const float4 x0 = *reinterpret_cast<const float4*>(&s_x[j][0]);
        const float4 x1 = *reinterpret_cast<const float4*>(&s_x[j][4]);
        acc[0] = fmaf(x0.x, wv, acc[0]);
        acc[1] = fmaf(x0.y, wv, acc[1]);
        acc[2] = fmaf(x0.z, wv, acc[2]);
        acc[3] = fmaf(x0.w, wv, acc[3]);
        acc[4] = fmaf(x1.x, wv, acc[4]);
        acc[5] = fmaf(x1.y, wv, acc[5]);
        acc[6] = fmaf(x1.z, wv, acc[6]);
        acc[7] = fmaf(x1.w, wv, acc[7]);
    }

    // --- phase 5: cross-kphase reduction + bias + store ---
    #pragma unroll
    for (int b = 0; b < B_; ++b) s_red[kphase][b][f] = acc[b];
    __syncthreads();

    {
        const int b  = t >> 5;
        const int ff = t & 31;
        float s = 0.f;
        #pragma unroll
        for (int p = 0; p < 8; ++p) s += s_red[p][b][ff];
        out[((size_t)b * F_ + ff) * N_ + n] = s + bias[(size_t)ff * N_ + n];
    }
}

extern "C" void kernel_launch(void* const* d_in, const int* in_sizes, int n_in,
                              void* d_out, int out_size, void* d_ws, size_t ws_size,
                              hipStream_t stream) {
    const float* x    = (const float*)d_in[0];
    const float* w    = (const float*)d_in[1];
    const float* bias = (const float*)d_in[2];
    const int*   em   = (const int*)d_in[3];
    float*       out  = (float*)d_out;

    snl_sparse2<<<dim3(N_), dim3(256), 0, stream>>>(x, w, bias, em, out);
}

// Round 6
// 20.839 us; speedup vs baseline: 1.3346x; 1.0096x over previous
//
#include <hip/hip_runtime.h>

// SparseNodeLinear, wave-autonomous sparse kernel:
//   out[b,f,n] = sum_{k: em[n,k]==0} x[b,k,n] * w[n,k,f] + bias[f,n]
// x: [B,K,N] f32, w: [N,K,F] f32, bias: [F,N] f32, em: [N,K] int32, out: [B,F,N] f32
// B=8, N=2048, K=2049, F=32.  ~34 active k per node (~8.5 per wave).
//
// One block per node; each wave handles its own discovered k's end-to-end with
// NO cross-wave barrier until the final reduction:
//   em loads -> ballot -> wave-local list (LDS, wave-coherent) ->
//   full-wave x gather (64 lanes = 8 slots x 8 batches) || w preload (overlapped)
//   -> FMA -> one barrier -> 8-partial reduction -> bias + store.

constexpr int N_ = 2048;
constexpr int K_ = 2049;
constexpr int F_ = 32;
constexpr int B_ = 8;
constexpr int CH = 9;     // ceil(K/256)
constexpr int WCAP = 48;  // per-wave active cap (mean 8.5, sigma 2.9; >13 sigma margin)

__global__ __launch_bounds__(256, 8) void snl_sparse3(
    const float* __restrict__ x,
    const float* __restrict__ w,
    const float* __restrict__ bias,
    const int*   __restrict__ em,
    float* __restrict__ out)
{
    const int bid  = blockIdx.x;
    const int n    = ((bid & 7) << 8) | (bid >> 3);   // XCD-contiguous n chunks
    const int t    = threadIdx.x;
    const int lane = t & 63;
    const int wid  = t >> 6;    // 0..3

    __shared__ int   s_idx[4][WCAP];        // wave-local active k lists
    __shared__ float s_x[4][WCAP][B_];      // wave-local gathered x
    __shared__ float s_red[8][B_][F_];      // partials: p = wid*2 + kphase2

    const int*   emn = em + (size_t)n * K_;
    const float* wn  = w  + (size_t)n * K_ * F_;

    // --- phase 1: 9 independent em loads (issued immediately) ---
    int emr[CH];
    #pragma unroll
    for (int c = 0; c < CH - 1; ++c) emr[c] = emn[c * 256 + t];
    emr[CH - 1] = (t == 0) ? emn[2048] : 1;   // K = 2049 tail

    // --- phase 2: wave-local ballot prefix -> wave-local ordered list ---
    const unsigned long long lowmask = (1ull << lane) - 1ull;
    int wcnt = 0;
    #pragma unroll
    for (int c = 0; c < CH; ++c) {
        const bool act = (emr[c] == 0);
        const unsigned long long bal = __ballot(act);
        const int pos = wcnt + __popcll(bal & lowmask);
        wcnt += __popcll(bal);
        if (act && pos < WCAP) s_idx[wid][pos] = c * 256 + t;
    }
    wcnt = (wcnt < WCAP) ? wcnt : WCAP;
    const int wcnt_p = (wcnt + 1) & ~1;        // pad to even
    if (lane == 0 && (wcnt & 1)) s_idx[wid][wcnt] = 0;   // pad slot: k=0, x zeroed below

    // --- phase 3a: full-wave x gather (wave-coherent, no barrier needed) ---
    {
        const int slot0 = lane >> 3;   // 0..7
        const int gb    = lane & 7;    // batch
        #pragma unroll
        for (int r = 0; r < 2; ++r) {              // covers wcnt_p <= 16 (typical: 1-2 rounds)
            const int slot = slot0 + r * 8;
            if (slot < wcnt_p) {
                float xv = 0.f;
                if (slot < wcnt) {
                    const int kj = s_idx[wid][slot];
                    xv = x[((size_t)gb * K_ + kj) * N_ + n];
                }
                s_x[wid][slot][gb] = xv;
            }
        }
        for (int slot = slot0 + 16; slot < wcnt_p; slot += 8) {   // fallback, ~never
            float xv = 0.f;
            if (slot < wcnt) xv = x[((size_t)gb * K_ + s_idx[wid][slot]) * N_ + n];
            s_x[wid][slot][gb] = xv;
        }
    }

    // --- phase 3b: w preload, overlapped with the x gather above ---
    const int kp2 = lane >> 5;    // 0..1
    const int f   = lane & 31;
    const int tc  = wcnt_p >> 1;  // uniform trips per half-wave
    float wr[8];
    #pragma unroll
    for (int i = 0; i < 8; ++i) {
        if (i < tc) {
            const int slot = kp2 + 2 * i;
            wr[i] = wn[(size_t)s_idx[wid][slot] * F_ + f];   // 2 rows x 128B per instr
        }
    }

    // --- phase 4: FMA over this wave's segment ---
    float acc[B_];
    #pragma unroll
    for (int b = 0; b < B_; ++b) acc[b] = 0.f;

    #pragma unroll
    for (int i = 0; i < 8; ++i) {
        if (i < tc) {
            const int slot = kp2 + 2 * i;
            const float4 x0 = *reinterpret_cast<const float4*>(&s_x[wid][slot][0]);
            const float4 x1 = *reinterpret_cast<const float4*>(&s_x[wid][slot][4]);
            const float wv = wr[i];
            acc[0] = fmaf(x0.x, wv, acc[0]);
            acc[1] = fmaf(x0.y, wv, acc[1]);
            acc[2] = fmaf(x0.z, wv, acc[2]);
            acc[3] = fmaf(x0.w, wv, acc[3]);
            acc[4] = fmaf(x1.x, wv, acc[4]);
            acc[5] = fmaf(x1.y, wv, acc[5]);
            acc[6] = fmaf(x1.z, wv, acc[6]);
            acc[7] = fmaf(x1.w, wv, acc[7]);
        }
    }
    for (int slot = kp2 + 16; slot < wcnt_p; slot += 2) {   // fallback, ~never
        const float wv = wn[(size_t)s_idx[wid][slot] * F_ + f];
        const float4 x0 = *reinterpret_cast<const float4*>(&s_x[wid][slot][0]);
        const float4 x1 = *reinterpret_cast<const float4*>(&s_x[wid][slot][4]);
        acc[0] = fmaf(x0.x, wv, acc[0]);
        acc[1] = fmaf(x0.y, wv, acc[1]);
        acc[2] = fmaf(x0.z, wv, acc[2]);
        acc[3] = fmaf(x0.w, wv, acc[3]);
        acc[4] = fmaf(x1.x, wv, acc[4]);
        acc[5] = fmaf(x1.y, wv, acc[5]);
        acc[6] = fmaf(x1.z, wv, acc[6]);
        acc[7] = fmaf(x1.w, wv, acc[7]);
    }

    // --- phase 5: cross-wave/kphase reduction + bias + store ---
    #pragma unroll
    for (int b = 0; b < B_; ++b) s_red[wid * 2 + kp2][b][f] = acc[b];
    __syncthreads();

    {
        const int b  = t >> 5;
        const int ff = t & 31;
        float s = 0.f;
        #pragma unroll
        for (int p = 0; p < 8; ++p) s += s_red[p][b][ff];
        out[((size_t)b * F_ + ff) * N_ + n] = s + bias[(size_t)ff * N_ + n];
    }
}

extern "C" void kernel_launch(void* const* d_in, const int* in_sizes, int n_in,
                              void* d_out, int out_size, void* d_ws, size_t ws_size,
                              hipStream_t stream) {
    const float* x    = (const float*)d_in[0];
    const float* w    = (const float*)d_in[1];
    const float* bias = (const float*)d_in[2];
    const int*   em   = (const int*)d_in[3];
    float*       out  = (float*)d_out;

    snl_sparse3<<<dim3(N_), dim3(256), 0, stream>>>(x, w, bias, em, out);
}